// Round 1
// baseline (8704.789 us; speedup 1.0000x reference)
//
#include <hip/hip_runtime.h>

#define NB 4
#define NPT 32768
#define CIN 128
#define COUT 256
#define NS 2048
#define THR_FPS 512
#define PTS_PER_T 64      // 32768 / 512
#define VD 34             // per-thread distances kept in VGPRs
#define LD 30             // per-thread distances kept in LDS

// ws float-offset layout
#define WS_G 0            // 128*128 Gram
#define WS_FSUM 16384     // 128 column sums of feat
#define WS_GSCALE 16512   // 256
#define WS_GBIAS 16768    // 256
#define WS_IDX 17024      // 8192 ints (B*S sample indices)

// d_out float-offset layout
#define OUT_COORD 0              // 8192*3
#define OUT_FEAT 24576           // 8192*256
#define OUT_OFFS 2121728         // 4

__global__ __launch_bounds__(512, 2) void fused1(
    const float* __restrict__ coord, const float* __restrict__ feat,
    float* __restrict__ wsf, int* __restrict__ wsi)
{
  __shared__ float lds_d[LD][THR_FPS];   // 61440 B
  __shared__ float s_c[3];
  __shared__ int s_widx[2];
  __shared__ int s_gmaxb[2];
  __shared__ float s_fs[4][128];

  const int bid = blockIdx.x;
  const int t = threadIdx.x;

  if (bid < NB) {
    // ---------------- FPS for cloud `bid` ----------------
    const float* xyz = coord + (size_t)bid * NPT * 3;
    int* idx_out = wsi + bid * NS;
    float px[PTS_PER_T], py[PTS_PER_T], pz[PTS_PER_T], dv[VD];
#pragma unroll
    for (int j = 0; j < PTS_PER_T; ++j) {
      int p = j * THR_FPS + t;
      px[j] = xyz[p * 3 + 0];
      py[j] = xyz[p * 3 + 1];
      pz[j] = xyz[p * 3 + 2];
    }
#pragma unroll
    for (int j = 0; j < VD; ++j) dv[j] = 1e10f;
#pragma unroll
    for (int g = 0; g < LD; ++g) lds_d[g][t] = 1e10f;
    if (t == 0) {
      idx_out[0] = 0;
      s_c[0] = xyz[0]; s_c[1] = xyz[1]; s_c[2] = xyz[2];
      s_widx[0] = s_widx[1] = 0x7fffffff;
      s_gmaxb[0] = s_gmaxb[1] = 0;   // distances >= 0, float bits monotone
    }
    __syncthreads();

    const int lane = t & 63;
    for (int it = 1; it < NS; ++it) {
      const int par = it & 1;
      const float cx = s_c[0], cy = s_c[1], cz = s_c[2];
      float lmax = -1.f;
      // exact numpy-f32 distance: squares as plain muls (asm blocks fma
      // contraction), sum as (sx+sy)+sz, min via v_min_f32.
#pragma unroll
      for (int j = 0; j < VD; ++j) {
        float dx = px[j] - cx, dy = py[j] - cy, dz = pz[j] - cz;
        float sx = dx * dx, sy = dy * dy, sz = dz * dz;
        asm volatile("" : "+v"(sx), "+v"(sy), "+v"(sz));
        float dist = (sx + sy) + sz;
        float nd = fminf(dv[j], dist);
        dv[j] = nd;
        lmax = fmaxf(lmax, nd);
      }
#pragma unroll
      for (int g = 0; g < LD; ++g) {
        const int j = VD + g;
        float dx = px[j] - cx, dy = py[j] - cy, dz = pz[j] - cz;
        float sx = dx * dx, sy = dy * dy, sz = dz * dz;
        asm volatile("" : "+v"(sx), "+v"(sy), "+v"(sz));
        float dist = (sx + sy) + sz;
        float nd = fminf(lds_d[g][t], dist);
        lds_d[g][t] = nd;
        lmax = fmaxf(lmax, nd);
      }
      // exact block max (fmax tree has no rounding)
      float wm = lmax;
#pragma unroll
      for (int o = 32; o > 0; o >>= 1) wm = fmaxf(wm, __shfl_xor(wm, o, 64));
      if (lane == 0) atomicMax(&s_gmaxb[par], __float_as_int(wm));
      __syncthreads();                                   // B0
      const float gmax = __int_as_float(s_gmaxb[par]);
      if (lmax == gmax) {                                // candidate threads only
        int bestp = 0x7fffffff;
#pragma unroll
        for (int j = 0; j < VD; ++j)
          if (dv[j] == gmax) bestp = min(bestp, j * THR_FPS + t);
#pragma unroll
        for (int g = 0; g < LD; ++g)
          if (lds_d[g][t] == gmax) bestp = min(bestp, (VD + g) * THR_FPS + t);
        atomicMin(&s_widx[par], bestp);                  // lowest index == np.argmax
      }
      __syncthreads();                                   // B1
      if (t == 0) {
        const int widx = s_widx[par];
        idx_out[it] = widx;
        s_c[0] = xyz[widx * 3 + 0];
        s_c[1] = xyz[widx * 3 + 1];
        s_c[2] = xyz[widx * 3 + 2];
        s_widx[par ^ 1] = 0x7fffffff;                    // reset other parity slot
        s_gmaxb[par ^ 1] = 0;
      }
      __syncthreads();                                   // B2
    }
  } else if (bid < NB + 128) {
    // ---------------- Gram partial: G += chunk^T chunk ----------------
    const int cb = bid - NB;
    const float* fr = feat + (size_t)cb * 1024 * CIN;
    const int ti = (t & 31) * 4;        // 0..124
    const int tj = (t >> 5) * 8;        // 0..120
    float acc[4][8];
#pragma unroll
    for (int a = 0; a < 4; ++a)
#pragma unroll
      for (int b2 = 0; b2 < 8; ++b2) acc[a][b2] = 0.f;
#pragma unroll 4
    for (int r = 0; r < 1024; ++r) {
      const float* rowp = fr + r * CIN;
      float4 a4 = *(const float4*)(rowp + ti);
      float4 b4 = *(const float4*)(rowp + tj);
      float4 b5 = *(const float4*)(rowp + tj + 4);
      float av[4] = {a4.x, a4.y, a4.z, a4.w};
      float bv[8] = {b4.x, b4.y, b4.z, b4.w, b5.x, b5.y, b5.z, b5.w};
#pragma unroll
      for (int a = 0; a < 4; ++a)
#pragma unroll
        for (int b2 = 0; b2 < 8; ++b2) acc[a][b2] += av[a] * bv[b2];
    }
    float* G = wsf + WS_G;
#pragma unroll
    for (int a = 0; a < 4; ++a)
#pragma unroll
      for (int b2 = 0; b2 < 8; ++b2)
        atomicAdd(&G[(ti + a) * CIN + (tj + b2)], acc[a][b2]);
  } else {
    // ---------------- column sums of feat ----------------
    const int fb = bid - NB - 128;      // 0..7
    const size_t base = (size_t)fb * 16384;
    const int c = t & 127, rg = t >> 7; // rg 0..3
    float s = 0.f;
    for (int r = rg; r < 16384; r += 4)
      s += feat[(base + r) * CIN + c];
    s_fs[rg][c] = s;
    __syncthreads();
    if (t < 128) {
      float v = s_fs[0][t] + s_fs[1][t] + s_fs[2][t] + s_fs[3][t];
      atomicAdd(&wsf[WS_FSUM + t], v);
    }
  }
}

// mean[c] = (fsum . W[c]) / M ; E[x^2][c] = W[c]^T G W[c] / M
__global__ __launch_bounds__(128) void finalize_k(
    const float* __restrict__ W, const float* __restrict__ gamma,
    const float* __restrict__ beta, float* __restrict__ wsf)
{
  const int c = blockIdx.x, i = threadIdx.x;
  const float* G = wsf + WS_G;
  const float* fsum = wsf + WS_FSUM;
  const float* Gi = G + i * CIN;
  const float* Wc = W + c * CIN;
  float td = 0.f;
#pragma unroll 8
  for (int j = 0; j < CIN; j += 4) {
    float4 g4 = *(const float4*)(Gi + j);
    float4 w4 = *(const float4*)(Wc + j);
    td += g4.x * w4.x + g4.y * w4.y + g4.z * w4.z + g4.w * w4.w;
  }
  const float wci = Wc[i];
  float q = wci * td;
  float m = fsum[i] * wci;
#pragma unroll
  for (int o = 32; o > 0; o >>= 1) {
    q += __shfl_xor(q, o, 64);
    m += __shfl_xor(m, o, 64);
  }
  __shared__ float sq[2], sm[2];
  if ((i & 63) == 0) { sq[i >> 6] = q; sm[i >> 6] = m; }
  __syncthreads();
  if (i == 0) {
    const float inv_m = 1.f / 131072.f;
    float mean = (sm[0] + sm[1]) * inv_m;
    float e2 = (sq[0] + sq[1]) * inv_m;
    float var = e2 - mean * mean;
    float rstd = rsqrtf(var + 1e-5f);
    float gs = gamma[c] * rstd;
    wsf[WS_GSCALE + c] = gs;
    wsf[WS_GBIAS + c] = beta[c] - mean * gs;
  }
}

// recompute x rows only at sampled indices, normalize + relu, gather coords
__global__ __launch_bounds__(256) void gather_k(
    const float* __restrict__ coord, const float* __restrict__ feat,
    const float* __restrict__ W, const float* __restrict__ wsf,
    const int* __restrict__ wsi, float* __restrict__ out)
{
  const int p = blockIdx.x, t = threadIdx.x;
  const int b = p >> 11;
  const int idx = wsi[p];
  const size_t row = (size_t)b * NPT + idx;
  __shared__ float lf[CIN];
  if (t < CIN) lf[t] = feat[row * CIN + t];
  __syncthreads();
  const float* Wc = W + t * CIN;
  float acc = 0.f;
#pragma unroll 8
  for (int k = 0; k < CIN; k += 4) {
    float4 w4 = *(const float4*)(Wc + k);
    acc += lf[k] * w4.x + lf[k + 1] * w4.y + lf[k + 2] * w4.z + lf[k + 3] * w4.w;
  }
  float y = fmaxf(fmaf(acc, wsf[WS_GSCALE + t], wsf[WS_GBIAS + t]), 0.f);
  out[OUT_FEAT + (size_t)p * COUT + t] = y;
  if (t < 3) out[OUT_COORD + p * 3 + t] = coord[row * 3 + t];
  if (p == 0 && t < 4) out[OUT_OFFS + t] = (float)((t + 1) * NS);
}

extern "C" void kernel_launch(void* const* d_in, const int* in_sizes, int n_in,
                              void* d_out, int out_size, void* d_ws, size_t ws_size,
                              hipStream_t stream)
{
  const float* coord = (const float*)d_in[0];
  const float* feat  = (const float*)d_in[1];
  // d_in[2] = offset (unused; implied by constants)
  const float* W     = (const float*)d_in[3];
  const float* gamma = (const float*)d_in[4];
  const float* beta  = (const float*)d_in[5];
  float* wsf = (float*)d_ws;
  int* wsi = (int*)(wsf + WS_IDX);
  float* out = (float*)d_out;

  // zero the Gram + column-sum accumulators (atomics accumulate into these)
  hipMemsetAsync(d_ws, 0, (WS_FSUM + 128) * sizeof(float), stream);

  fused1<<<NB + 128 + 8, THR_FPS, 0, stream>>>(coord, feat, wsf, wsi);
  finalize_k<<<COUT, 128, 0, stream>>>(W, gamma, beta, wsf);
  gather_k<<<NB * NS, 256, 0, stream>>>(coord, feat, W, wsf, wsi, out);
}

// Round 2
// 8227.053 us; speedup vs baseline: 1.0581x; 1.0581x over previous
//
#include <hip/hip_runtime.h>

#define NB 4
#define NPT 32768
#define CIN 128
#define COUT 256
#define NS 2048
#define THR_FPS 512
#define PTS_PER_T 64      // 32768 / 512
#define VD 34             // per-thread distances kept in VGPRs
#define LD 30             // per-thread distances kept in LDS

// ws float-offset layout
#define WS_G 0            // 128*128 Gram
#define WS_FSUM 16384     // 128 column sums of feat
#define WS_GSCALE 16512   // 256
#define WS_GBIAS 16768    // 256
#define WS_IDX 17024      // 8192 ints (B*S sample indices)

// d_out float-offset layout
#define OUT_COORD 0              // 8192*3
#define OUT_FEAT 24576           // 8192*256
#define OUT_OFFS 2121728         // 4

// launch_bounds(512,1): CUDA-semantics min 1 block/CU -> 8 waves/CU ->
// 2 waves/SIMD -> 256-VGPR budget. (512,2) gave 128 VGPRs and spilled
// the 226-reg FPS state to scratch (round-1: WRITE_SIZE 65 MB of spill).
__global__ __launch_bounds__(512, 1) void fused1(
    const float* __restrict__ coord, const float* __restrict__ feat,
    float* __restrict__ wsf, int* __restrict__ wsi)
{
  __shared__ float lds_d[LD][THR_FPS];   // 61440 B
  __shared__ int s_widx[2];
  __shared__ int s_gmaxb[2];
  __shared__ float s_fs[4][128];

  const int bid = blockIdx.x;
  const int t = threadIdx.x;

  if (bid < NB) {
    // ---------------- FPS for cloud `bid` ----------------
    const float* xyz = coord + (size_t)bid * NPT * 3;
    int* idx_out = wsi + bid * NS;
    float px[PTS_PER_T], py[PTS_PER_T], pz[PTS_PER_T], dv[VD];
#pragma unroll
    for (int j = 0; j < PTS_PER_T; ++j) {
      int p = j * THR_FPS + t;
      px[j] = xyz[p * 3 + 0];
      py[j] = xyz[p * 3 + 1];
      pz[j] = xyz[p * 3 + 2];
    }
#pragma unroll
    for (int j = 0; j < VD; ++j) dv[j] = 1e10f;
#pragma unroll
    for (int g = 0; g < LD; ++g) lds_d[g][t] = 1e10f;
    if (t == 0) {
      idx_out[0] = 0;
      s_widx[0] = s_widx[1] = 0x7fffffff;
      s_gmaxb[0] = s_gmaxb[1] = 0;   // distances >= 0, float bits monotone
    }
    // all threads read centroid 0 directly (same-address broadcast load)
    float cx = xyz[0], cy = xyz[1], cz = xyz[2];
    __syncthreads();

    const int lane = t & 63;
    for (int it = 1; it < NS; ++it) {
      const int par = it & 1;
      float mx[4] = {-1.f, -1.f, -1.f, -1.f};   // 4 parallel max accumulators
      // exact numpy-f32 distance: squares as plain muls (asm blocks fma
      // contraction), sum as (sx+sy)+sz, min via v_min_f32.
#pragma unroll
      for (int j = 0; j < VD; ++j) {
        float dx = px[j] - cx, dy = py[j] - cy, dz = pz[j] - cz;
        float sx = dx * dx, sy = dy * dy, sz = dz * dz;
        asm volatile("" : "+v"(sx), "+v"(sy), "+v"(sz));
        float nd = fminf(dv[j], (sx + sy) + sz);
        dv[j] = nd;
        mx[j & 3] = fmaxf(mx[j & 3], nd);
      }
#pragma unroll
      for (int g = 0; g < LD; ++g) {
        const int j = VD + g;
        float dx = px[j] - cx, dy = py[j] - cy, dz = pz[j] - cz;
        float sx = dx * dx, sy = dy * dy, sz = dz * dz;
        asm volatile("" : "+v"(sx), "+v"(sy), "+v"(sz));
        float nd = fminf(lds_d[g][t], (sx + sy) + sz);
        lds_d[g][t] = nd;
        mx[(j & 3)] = fmaxf(mx[j & 3], nd);
      }
      float lmax = fmaxf(fmaxf(mx[0], mx[1]), fmaxf(mx[2], mx[3]));
      // exact block max (fmax tree has no rounding)
      float wm = lmax;
#pragma unroll
      for (int o = 32; o > 0; o >>= 1) wm = fmaxf(wm, __shfl_xor(wm, o, 64));
      if (lane == 0) atomicMax(&s_gmaxb[par], __float_as_int(wm));
      __syncthreads();                                   // B0
      // reset other-parity slots: barrier-ordered (B0 behind, B1 ahead)
      if (t == 0) { s_gmaxb[par ^ 1] = 0; s_widx[par ^ 1] = 0x7fffffff; }
      const float gmax = __int_as_float(s_gmaxb[par]);
      if (lmax == gmax) {                                // candidate threads only
        int bestp = 0x7fffffff;
#pragma unroll
        for (int j = 0; j < VD; ++j)
          if (dv[j] == gmax) bestp = min(bestp, j * THR_FPS + t);
#pragma unroll
        for (int g = 0; g < LD; ++g)
          if (lds_d[g][t] == gmax) bestp = min(bestp, (VD + g) * THR_FPS + t);
        atomicMin(&s_widx[par], bestp);                  // lowest index == np.argmax
      }
      __syncthreads();                                   // B1
      const int widx = s_widx[par];
      if (t == 0) idx_out[it] = widx;
      // all threads fetch new centroid: same address -> one broadcast load
      cx = xyz[widx * 3 + 0];
      cy = xyz[widx * 3 + 1];
      cz = xyz[widx * 3 + 2];
    }
  } else if (bid < NB + 128) {
    // ---------------- Gram partial: G += chunk^T chunk ----------------
    const int cb = bid - NB;
    const float* fr = feat + (size_t)cb * 1024 * CIN;
    const int ti = (t & 31) * 4;        // 0..124
    const int tj = (t >> 5) * 8;        // 0..120
    float acc[4][8];
#pragma unroll
    for (int a = 0; a < 4; ++a)
#pragma unroll
      for (int b2 = 0; b2 < 8; ++b2) acc[a][b2] = 0.f;
#pragma unroll 4
    for (int r = 0; r < 1024; ++r) {
      const float* rowp = fr + r * CIN;
      float4 a4 = *(const float4*)(rowp + ti);
      float4 b4 = *(const float4*)(rowp + tj);
      float4 b5 = *(const float4*)(rowp + tj + 4);
      float av[4] = {a4.x, a4.y, a4.z, a4.w};
      float bv[8] = {b4.x, b4.y, b4.z, b4.w, b5.x, b5.y, b5.z, b5.w};
#pragma unroll
      for (int a = 0; a < 4; ++a)
#pragma unroll
        for (int b2 = 0; b2 < 8; ++b2) acc[a][b2] += av[a] * bv[b2];
    }
    float* G = wsf + WS_G;
#pragma unroll
    for (int a = 0; a < 4; ++a)
#pragma unroll
      for (int b2 = 0; b2 < 8; ++b2)
        atomicAdd(&G[(ti + a) * CIN + (tj + b2)], acc[a][b2]);
  } else {
    // ---------------- column sums of feat ----------------
    const int fb = bid - NB - 128;      // 0..7
    const size_t base = (size_t)fb * 16384;
    const int c = t & 127, rg = t >> 7; // rg 0..3
    float s = 0.f;
    for (int r = rg; r < 16384; r += 4)
      s += feat[(base + r) * CIN + c];
    s_fs[rg][c] = s;
    __syncthreads();
    if (t < 128) {
      float v = s_fs[0][t] + s_fs[1][t] + s_fs[2][t] + s_fs[3][t];
      atomicAdd(&wsf[WS_FSUM + t], v);
    }
  }
}

// mean[c] = (fsum . W[c]) / M ; E[x^2][c] = W[c]^T G W[c] / M
__global__ __launch_bounds__(128) void finalize_k(
    const float* __restrict__ W, const float* __restrict__ gamma,
    const float* __restrict__ beta, float* __restrict__ wsf)
{
  const int c = blockIdx.x, i = threadIdx.x;
  const float* G = wsf + WS_G;
  const float* fsum = wsf + WS_FSUM;
  const float* Gi = G + i * CIN;
  const float* Wc = W + c * CIN;
  float td = 0.f;
#pragma unroll 8
  for (int j = 0; j < CIN; j += 4) {
    float4 g4 = *(const float4*)(Gi + j);
    float4 w4 = *(const float4*)(Wc + j);
    td += g4.x * w4.x + g4.y * w4.y + g4.z * w4.z + g4.w * w4.w;
  }
  const float wci = Wc[i];
  float q = wci * td;
  float m = fsum[i] * wci;
#pragma unroll
  for (int o = 32; o > 0; o >>= 1) {
    q += __shfl_xor(q, o, 64);
    m += __shfl_xor(m, o, 64);
  }
  __shared__ float sq[2], sm[2];
  if ((i & 63) == 0) { sq[i >> 6] = q; sm[i >> 6] = m; }
  __syncthreads();
  if (i == 0) {
    const float inv_m = 1.f / 131072.f;
    float mean = (sm[0] + sm[1]) * inv_m;
    float e2 = (sq[0] + sq[1]) * inv_m;
    float var = e2 - mean * mean;
    float rstd = rsqrtf(var + 1e-5f);
    float gs = gamma[c] * rstd;
    wsf[WS_GSCALE + c] = gs;
    wsf[WS_GBIAS + c] = beta[c] - mean * gs;
  }
}

// recompute x rows only at sampled indices, normalize + relu, gather coords
__global__ __launch_bounds__(256) void gather_k(
    const float* __restrict__ coord, const float* __restrict__ feat,
    const float* __restrict__ W, const float* __restrict__ wsf,
    const int* __restrict__ wsi, float* __restrict__ out)
{
  const int p = blockIdx.x, t = threadIdx.x;
  const int b = p >> 11;
  const int idx = wsi[p];
  const size_t row = (size_t)b * NPT + idx;
  __shared__ float lf[CIN];
  if (t < CIN) lf[t] = feat[row * CIN + t];
  __syncthreads();
  const float* Wc = W + t * CIN;
  float acc = 0.f;
#pragma unroll 8
  for (int k = 0; k < CIN; k += 4) {
    float4 w4 = *(const float4*)(Wc + k);
    acc += lf[k] * w4.x + lf[k + 1] * w4.y + lf[k + 2] * w4.z + lf[k + 3] * w4.w;
  }
  float y = fmaxf(fmaf(acc, wsf[WS_GSCALE + t], wsf[WS_GBIAS + t]), 0.f);
  out[OUT_FEAT + (size_t)p * COUT + t] = y;
  if (t < 3) out[OUT_COORD + p * 3 + t] = coord[row * 3 + t];
  if (p == 0 && t < 4) out[OUT_OFFS + t] = (float)((t + 1) * NS);
}

extern "C" void kernel_launch(void* const* d_in, const int* in_sizes, int n_in,
                              void* d_out, int out_size, void* d_ws, size_t ws_size,
                              hipStream_t stream)
{
  const float* coord = (const float*)d_in[0];
  const float* feat  = (const float*)d_in[1];
  // d_in[2] = offset (unused; implied by constants)
  const float* W     = (const float*)d_in[3];
  const float* gamma = (const float*)d_in[4];
  const float* beta  = (const float*)d_in[5];
  float* wsf = (float*)d_ws;
  int* wsi = (int*)(wsf + WS_IDX);
  float* out = (float*)d_out;

  // zero the Gram + column-sum accumulators (atomics accumulate into these)
  hipMemsetAsync(d_ws, 0, (WS_FSUM + 128) * sizeof(float), stream);

  fused1<<<NB + 128 + 8, THR_FPS, 0, stream>>>(coord, feat, wsf, wsi);
  finalize_k<<<COUT, 128, 0, stream>>>(W, gamma, beta, wsf);
  gather_k<<<NB * NS, 256, 0, stream>>>(coord, feat, W, wsf, wsi, out);
}

// Round 3
// 8224.505 us; speedup vs baseline: 1.0584x; 1.0003x over previous
//
#include <hip/hip_runtime.h>

#define NB 4
#define NPT 32768
#define CIN 128
#define COUT 256
#define NS 2048
#define THR_FPS 512
#define PTS_PER_T 64      // 32768 / 512
#define VD 34             // per-thread distances kept in VGPRs
#define LD 30             // per-thread distances kept in LDS

// ws float-offset layout
#define WS_G 0            // 128*128 Gram
#define WS_FSUM 16384     // 128 column sums of feat
#define WS_GSCALE 16512   // 256
#define WS_GBIAS 16768    // 256
#define WS_IDX 17024      // 8192 ints (B*S sample indices)

// d_out float-offset layout
#define OUT_COORD 0              // 8192*3
#define OUT_FEAT 24576           // 8192*256
#define OUT_OFFS 2121728         // 4

// Register budget fight (rounds 1-2): static LDS of 61.4 KB lets 2 blocks/CU
// fit, so LLVM's occupancy heuristic targets 4 waves/SIMD and clamps the
// VGPR budget to 128 REGARDLESS of __launch_bounds__ -> 246 live regs spill
// (65 MB/dispatch scratch write-through). amdgpu_num_vgpr(256) sets the
// allocator cap directly, bypassing the LDS-occupancy clamp.
__global__ __attribute__((amdgpu_flat_work_group_size(512, 512),
                          amdgpu_waves_per_eu(1, 2),
                          amdgpu_num_vgpr(256)))
void fused1(
    const float* __restrict__ coord, const float* __restrict__ feat,
    float* __restrict__ wsf, int* __restrict__ wsi)
{
  __shared__ float lds_d[LD][THR_FPS];   // 61440 B
  __shared__ int s_widx[2];
  __shared__ int s_gmaxb[2];
  __shared__ float s_fs[4][128];

  const int bid = blockIdx.x;
  const int t = threadIdx.x;

  if (bid < NB) {
    // ---------------- FPS for cloud `bid` ----------------
    const float* xyz = coord + (size_t)bid * NPT * 3;
    int* idx_out = wsi + bid * NS;
    float px[PTS_PER_T], py[PTS_PER_T], pz[PTS_PER_T], dv[VD];
#pragma unroll
    for (int j = 0; j < PTS_PER_T; ++j) {
      int p = j * THR_FPS + t;
      px[j] = xyz[p * 3 + 0];
      py[j] = xyz[p * 3 + 1];
      pz[j] = xyz[p * 3 + 2];
    }
#pragma unroll
    for (int j = 0; j < VD; ++j) dv[j] = 1e10f;
#pragma unroll
    for (int g = 0; g < LD; ++g) lds_d[g][t] = 1e10f;
    if (t == 0) {
      idx_out[0] = 0;
      s_widx[0] = s_widx[1] = 0x7fffffff;
      s_gmaxb[0] = s_gmaxb[1] = 0;   // distances >= 0, float bits monotone
    }
    // all threads read centroid 0 directly (same-address broadcast load)
    float cx = xyz[0], cy = xyz[1], cz = xyz[2];
    __syncthreads();

    const int lane = t & 63;
    for (int it = 1; it < NS; ++it) {
      const int par = it & 1;
      float mx[4] = {-1.f, -1.f, -1.f, -1.f};   // 4 parallel max accumulators
      // exact numpy-f32 distance: squares as plain muls (asm blocks fma
      // contraction), sum as (sx+sy)+sz, min via v_min_f32.
#pragma unroll
      for (int j = 0; j < VD; ++j) {
        float dx = px[j] - cx, dy = py[j] - cy, dz = pz[j] - cz;
        float sx = dx * dx, sy = dy * dy, sz = dz * dz;
        asm volatile("" : "+v"(sx), "+v"(sy), "+v"(sz));
        float nd = fminf(dv[j], (sx + sy) + sz);
        dv[j] = nd;
        mx[j & 3] = fmaxf(mx[j & 3], nd);
      }
#pragma unroll
      for (int g = 0; g < LD; ++g) {
        const int j = VD + g;
        float dx = px[j] - cx, dy = py[j] - cy, dz = pz[j] - cz;
        float sx = dx * dx, sy = dy * dy, sz = dz * dz;
        asm volatile("" : "+v"(sx), "+v"(sy), "+v"(sz));
        float nd = fminf(lds_d[g][t], (sx + sy) + sz);
        lds_d[g][t] = nd;
        mx[(j & 3)] = fmaxf(mx[j & 3], nd);
      }
      float lmax = fmaxf(fmaxf(mx[0], mx[1]), fmaxf(mx[2], mx[3]));
      // exact block max (fmax tree has no rounding)
      float wm = lmax;
#pragma unroll
      for (int o = 32; o > 0; o >>= 1) wm = fmaxf(wm, __shfl_xor(wm, o, 64));
      if (lane == 0) atomicMax(&s_gmaxb[par], __float_as_int(wm));
      __syncthreads();                                   // B0
      // reset other-parity slots: barrier-ordered (B0 behind, B1 ahead)
      if (t == 0) { s_gmaxb[par ^ 1] = 0; s_widx[par ^ 1] = 0x7fffffff; }
      const float gmax = __int_as_float(s_gmaxb[par]);
      if (lmax == gmax) {                                // candidate threads only
        int bestp = 0x7fffffff;
#pragma unroll
        for (int j = 0; j < VD; ++j)
          if (dv[j] == gmax) bestp = min(bestp, j * THR_FPS + t);
#pragma unroll
        for (int g = 0; g < LD; ++g)
          if (lds_d[g][t] == gmax) bestp = min(bestp, (VD + g) * THR_FPS + t);
        atomicMin(&s_widx[par], bestp);                  // lowest index == np.argmax
      }
      __syncthreads();                                   // B1
      const int widx = s_widx[par];
      if (t == 0) idx_out[it] = widx;
      // all threads fetch new centroid: same address -> one broadcast load
      cx = xyz[widx * 3 + 0];
      cy = xyz[widx * 3 + 1];
      cz = xyz[widx * 3 + 2];
    }
  } else if (bid < NB + 128) {
    // ---------------- Gram partial: G += chunk^T chunk ----------------
    const int cb = bid - NB;
    const float* fr = feat + (size_t)cb * 1024 * CIN;
    const int ti = (t & 31) * 4;        // 0..124
    const int tj = (t >> 5) * 8;        // 0..120
    float acc[4][8];
#pragma unroll
    for (int a = 0; a < 4; ++a)
#pragma unroll
      for (int b2 = 0; b2 < 8; ++b2) acc[a][b2] = 0.f;
#pragma unroll 4
    for (int r = 0; r < 1024; ++r) {
      const float* rowp = fr + r * CIN;
      float4 a4 = *(const float4*)(rowp + ti);
      float4 b4 = *(const float4*)(rowp + tj);
      float4 b5 = *(const float4*)(rowp + tj + 4);
      float av[4] = {a4.x, a4.y, a4.z, a4.w};
      float bv[8] = {b4.x, b4.y, b4.z, b4.w, b5.x, b5.y, b5.z, b5.w};
#pragma unroll
      for (int a = 0; a < 4; ++a)
#pragma unroll
        for (int b2 = 0; b2 < 8; ++b2) acc[a][b2] += av[a] * bv[b2];
    }
    float* G = wsf + WS_G;
#pragma unroll
    for (int a = 0; a < 4; ++a)
#pragma unroll
      for (int b2 = 0; b2 < 8; ++b2)
        atomicAdd(&G[(ti + a) * CIN + (tj + b2)], acc[a][b2]);
  } else {
    // ---------------- column sums of feat ----------------
    const int fb = bid - NB - 128;      // 0..7
    const size_t base = (size_t)fb * 16384;
    const int c = t & 127, rg = t >> 7; // rg 0..3
    float s = 0.f;
    for (int r = rg; r < 16384; r += 4)
      s += feat[(base + r) * CIN + c];
    s_fs[rg][c] = s;
    __syncthreads();
    if (t < 128) {
      float v = s_fs[0][t] + s_fs[1][t] + s_fs[2][t] + s_fs[3][t];
      atomicAdd(&wsf[WS_FSUM + t], v);
    }
  }
}

// mean[c] = (fsum . W[c]) / M ; E[x^2][c] = W[c]^T G W[c] / M
__global__ __launch_bounds__(128) void finalize_k(
    const float* __restrict__ W, const float* __restrict__ gamma,
    const float* __restrict__ beta, float* __restrict__ wsf)
{
  const int c = blockIdx.x, i = threadIdx.x;
  const float* G = wsf + WS_G;
  const float* fsum = wsf + WS_FSUM;
  const float* Gi = G + i * CIN;
  const float* Wc = W + c * CIN;
  float td = 0.f;
#pragma unroll 8
  for (int j = 0; j < CIN; j += 4) {
    float4 g4 = *(const float4*)(Gi + j);
    float4 w4 = *(const float4*)(Wc + j);
    td += g4.x * w4.x + g4.y * w4.y + g4.z * w4.z + g4.w * w4.w;
  }
  const float wci = Wc[i];
  float q = wci * td;
  float m = fsum[i] * wci;
#pragma unroll
  for (int o = 32; o > 0; o >>= 1) {
    q += __shfl_xor(q, o, 64);
    m += __shfl_xor(m, o, 64);
  }
  __shared__ float sq[2], sm[2];
  if ((i & 63) == 0) { sq[i >> 6] = q; sm[i >> 6] = m; }
  __syncthreads();
  if (i == 0) {
    const float inv_m = 1.f / 131072.f;
    float mean = (sm[0] + sm[1]) * inv_m;
    float e2 = (sq[0] + sq[1]) * inv_m;
    float var = e2 - mean * mean;
    float rstd = rsqrtf(var + 1e-5f);
    float gs = gamma[c] * rstd;
    wsf[WS_GSCALE + c] = gs;
    wsf[WS_GBIAS + c] = beta[c] - mean * gs;
  }
}

// recompute x rows only at sampled indices, normalize + relu, gather coords
__global__ __launch_bounds__(256) void gather_k(
    const float* __restrict__ coord, const float* __restrict__ feat,
    const float* __restrict__ W, const float* __restrict__ wsf,
    const int* __restrict__ wsi, float* __restrict__ out)
{
  const int p = blockIdx.x, t = threadIdx.x;
  const int b = p >> 11;
  const int idx = wsi[p];
  const size_t row = (size_t)b * NPT + idx;
  __shared__ float lf[CIN];
  if (t < CIN) lf[t] = feat[row * CIN + t];
  __syncthreads();
  const float* Wc = W + t * CIN;
  float acc = 0.f;
#pragma unroll 8
  for (int k = 0; k < CIN; k += 4) {
    float4 w4 = *(const float4*)(Wc + k);
    acc += lf[k] * w4.x + lf[k + 1] * w4.y + lf[k + 2] * w4.z + lf[k + 3] * w4.w;
  }
  float y = fmaxf(fmaf(acc, wsf[WS_GSCALE + t], wsf[WS_GBIAS + t]), 0.f);
  out[OUT_FEAT + (size_t)p * COUT + t] = y;
  if (t < 3) out[OUT_COORD + p * 3 + t] = coord[row * 3 + t];
  if (p == 0 && t < 4) out[OUT_OFFS + t] = (float)((t + 1) * NS);
}

extern "C" void kernel_launch(void* const* d_in, const int* in_sizes, int n_in,
                              void* d_out, int out_size, void* d_ws, size_t ws_size,
                              hipStream_t stream)
{
  const float* coord = (const float*)d_in[0];
  const float* feat  = (const float*)d_in[1];
  // d_in[2] = offset (unused; implied by constants)
  const float* W     = (const float*)d_in[3];
  const float* gamma = (const float*)d_in[4];
  const float* beta  = (const float*)d_in[5];
  float* wsf = (float*)d_ws;
  int* wsi = (int*)(wsf + WS_IDX);
  float* out = (float*)d_out;

  // zero the Gram + column-sum accumulators (atomics accumulate into these)
  hipMemsetAsync(d_ws, 0, (WS_FSUM + 128) * sizeof(float), stream);

  fused1<<<NB + 128 + 8, THR_FPS, 0, stream>>>(coord, feat, wsf, wsi);
  finalize_k<<<COUT, 128, 0, stream>>>(W, gamma, beta, wsf);
  gather_k<<<NB * NS, 256, 0, stream>>>(coord, feat, W, wsf, wsi, out);
}

// Round 5
// 8025.855 us; speedup vs baseline: 1.0846x; 1.0248x over previous
//
#include <hip/hip_runtime.h>

#define NB 4
#define NPT 32768
#define CIN 128
#define COUT 256
#define NS 2048
#define THR 512
#define PPT 64            // points per thread (NPT / THR)
#define VD 34             // per-thread distances kept in VGPRs
#define LD2 15            // float2 LDS rows actually used (30 scalar rows)
#define LDS_ROWS 40       // ALLOCATED scalar rows: 40*512*4 = 81920 B

// ws float-offset layout
#define WS_G 0            // 128*128 Gram
#define WS_FSUM 16384     // 128 column sums
#define WS_GSCALE 16512   // 256
#define WS_GBIAS 16768    // 256
#define WS_IDX 17024      // 8192 ints (B*S sample indices)

// d_out float-offset layout
#define OUT_COORD 0
#define OUT_FEAT 24576
#define OUT_OFFS 2121728

// Register-budget mechanism (established rounds 1-3): the backend pins the
// per-wave VGPR cap to 512 / (LDS-derived waves per EU) and ignores
// launch_bounds / amdgpu_* attributes. 61.4 KB LDS -> 2 blocks/CU -> 4
// waves/EU -> 128-reg cap -> the 246-reg FPS state spilled 65 MB/launch.
// Fix: ALLOCATE >80 KB LDS (only 30 rows used) -> 1 block/CU -> 2 waves/EU
// -> 256-reg budget -> no spills. FPS wants 1 block/CU anyway; all 140
// blocks still co-resident on 256 CUs.
__global__ __launch_bounds__(THR) void fused1(
    const float* __restrict__ coord, const float* __restrict__ feat,
    float* __restrict__ wsf, int* __restrict__ wsi)
{
  __shared__ float lds_raw[LDS_ROWS * THR];   // 81920 B (deliberately oversized)
  __shared__ int s_widx[2];
  __shared__ int s_gmaxb[2];
  __shared__ float s_fs[4][128];

  const int bid = blockIdx.x;
  const int t = threadIdx.x;

  if (bid < NB) {
    // ---------------- FPS for cloud `bid` (single block per cloud) ----------
    const float* xyz = coord + (size_t)bid * NPT * 3;
    int* idx_out = wsi + bid * NS;
    float2* l2 = ((float2*)lds_raw) + t;      // column t; row stride THR float2s

    float px[PPT], py[PPT], pz[PPT], dv[VD];
#pragma unroll
    for (int j = 0; j < PPT; ++j) {
      int p = j * THR + t;
      px[j] = xyz[p * 3 + 0];
      py[j] = xyz[p * 3 + 1];
      pz[j] = xyz[p * 3 + 2];
    }
#pragma unroll
    for (int j = 0; j < VD; ++j) dv[j] = 1e10f;
#pragma unroll
    for (int g = 0; g < LD2; ++g) l2[g * THR] = make_float2(1e10f, 1e10f);
    if (t == 0) {
      idx_out[0] = 0;
      s_widx[0] = s_widx[1] = 0x7fffffff;
      s_gmaxb[0] = s_gmaxb[1] = 0;   // distances >= 0 -> float bits monotone
    }
    float cx = xyz[0], cy = xyz[1], cz = xyz[2];   // same-address broadcast load
    __syncthreads();

    const int lane = t & 63;
    for (int it = 1; it < NS; ++it) {
      const int par = it & 1;
      float mx[4] = {-1.f, -1.f, -1.f, -1.f};
      // exact numpy-f32 distance: plain muls (asm blocks fma contraction),
      // (sx+sy)+sz, v_min_f32 update.
#pragma unroll
      for (int j = 0; j < VD; ++j) {
        float dx = px[j] - cx, dy = py[j] - cy, dz = pz[j] - cz;
        float sx = dx * dx, sy = dy * dy, sz = dz * dz;
        asm volatile("" : "+v"(sx), "+v"(sy), "+v"(sz));
        float nd = fminf(dv[j], (sx + sy) + sz);
        dv[j] = nd;
        mx[j & 3] = fmaxf(mx[j & 3], nd);
      }
#pragma unroll
      for (int g = 0; g < LD2; ++g) {
        const int j0 = VD + 2 * g, j1 = j0 + 1;
        float dx0 = px[j0] - cx, dy0 = py[j0] - cy, dz0 = pz[j0] - cz;
        float sx0 = dx0 * dx0, sy0 = dy0 * dy0, sz0 = dz0 * dz0;
        asm volatile("" : "+v"(sx0), "+v"(sy0), "+v"(sz0));
        float d0 = (sx0 + sy0) + sz0;
        float dx1 = px[j1] - cx, dy1 = py[j1] - cy, dz1 = pz[j1] - cz;
        float sx1 = dx1 * dx1, sy1 = dy1 * dy1, sz1 = dz1 * dz1;
        asm volatile("" : "+v"(sx1), "+v"(sy1), "+v"(sz1));
        float d1 = (sx1 + sy1) + sz1;
        float2 v = l2[g * THR];                    // ds_read_b64
        v.x = fminf(v.x, d0);
        v.y = fminf(v.y, d1);
        l2[g * THR] = v;                           // ds_write_b64
        mx[g & 3] = fmaxf(mx[g & 3], fmaxf(v.x, v.y));
      }
      float lmax = fmaxf(fmaxf(mx[0], mx[1]), fmaxf(mx[2], mx[3]));
      // exact block max (fmax tree has no rounding)
      float wm = lmax;
#pragma unroll
      for (int o = 32; o > 0; o >>= 1) wm = fmaxf(wm, __shfl_xor(wm, o, 64));
      if (lane == 0) atomicMax(&s_gmaxb[par], __float_as_int(wm));
      __syncthreads();                                   // B0
      // reset other-parity slots: barrier-ordered (B0 behind, B1 ahead)
      if (t == 0) { s_gmaxb[par ^ 1] = 0; s_widx[par ^ 1] = 0x7fffffff; }
      const float gmax = __int_as_float(s_gmaxb[par]);
      if (lmax == gmax) {                                // candidate threads only
        int best = 0x7fffffff;
#pragma unroll
        for (int j = 0; j < VD; ++j)
          if (dv[j] == gmax) best = min(best, j * THR + t);
#pragma unroll
        for (int g = 0; g < LD2; ++g) {
          float2 v = l2[g * THR];
          if (v.x == gmax) best = min(best, (VD + 2 * g) * THR + t);
          if (v.y == gmax) best = min(best, (VD + 2 * g + 1) * THR + t);
        }
        atomicMin(&s_widx[par], best);                   // lowest idx == np.argmax
      }
      __syncthreads();                                   // B1
      const int widx = s_widx[par];
      if (t == 0) idx_out[it] = widx;
      // all threads fetch new centroid: same address -> one broadcast load
      cx = xyz[widx * 3 + 0];
      cy = xyz[widx * 3 + 1];
      cz = xyz[widx * 3 + 2];
    }
  } else if (bid < NB + 128) {
    // ---------------- Gram partial: G += chunk^T chunk ----------------
    const int cb = bid - NB;
    const float* fr = feat + (size_t)cb * 1024 * CIN;
    const int ti = (t & 31) * 4;        // 0..124
    const int tj = (t >> 5) * 8;        // 0..120
    float acc[4][8];
#pragma unroll
    for (int a = 0; a < 4; ++a)
#pragma unroll
      for (int b2 = 0; b2 < 8; ++b2) acc[a][b2] = 0.f;
#pragma unroll 4
    for (int r = 0; r < 1024; ++r) {
      const float* rowp = fr + r * CIN;
      float4 a4 = *(const float4*)(rowp + ti);
      float4 b4 = *(const float4*)(rowp + tj);
      float4 b5 = *(const float4*)(rowp + tj + 4);
      float av[4] = {a4.x, a4.y, a4.z, a4.w};
      float bv[8] = {b4.x, b4.y, b4.z, b4.w, b5.x, b5.y, b5.z, b5.w};
#pragma unroll
      for (int a = 0; a < 4; ++a)
#pragma unroll
        for (int b2 = 0; b2 < 8; ++b2) acc[a][b2] += av[a] * bv[b2];
    }
    float* G = wsf + WS_G;
#pragma unroll
    for (int a = 0; a < 4; ++a)
#pragma unroll
      for (int b2 = 0; b2 < 8; ++b2)
        atomicAdd(&G[(ti + a) * CIN + (tj + b2)], acc[a][b2]);
  } else {
    // ---------------- column sums of feat ----------------
    const int fb = bid - NB - 128;      // 0..7
    const size_t base = (size_t)fb * 16384;
    const int c = t & 127, rg = t >> 7; // rg 0..3
    float s = 0.f;
    for (int r = rg; r < 16384; r += 4)
      s += feat[(base + r) * CIN + c];
    s_fs[rg][c] = s;
    __syncthreads();
    if (t < 128) {
      float v = s_fs[0][t] + s_fs[1][t] + s_fs[2][t] + s_fs[3][t];
      atomicAdd(&wsf[WS_FSUM + t], v);
    }
  }
}

// mean[c] = (fsum . W[c]) / M ; E[x^2][c] = W[c]^T G W[c] / M
__global__ __launch_bounds__(128) void finalize_k(
    const float* __restrict__ W, const float* __restrict__ gamma,
    const float* __restrict__ beta, float* __restrict__ wsf)
{
  const int c = blockIdx.x, i = threadIdx.x;
  const float* G = wsf + WS_G;
  const float* fsum = wsf + WS_FSUM;
  const float* Gi = G + i * CIN;
  const float* Wc = W + c * CIN;
  float td = 0.f;
#pragma unroll 8
  for (int j = 0; j < CIN; j += 4) {
    float4 g4 = *(const float4*)(Gi + j);
    float4 w4 = *(const float4*)(Wc + j);
    td += g4.x * w4.x + g4.y * w4.y + g4.z * w4.z + g4.w * w4.w;
  }
  const float wci = Wc[i];
  float q = wci * td;
  float m = fsum[i] * wci;
#pragma unroll
  for (int o = 32; o > 0; o >>= 1) {
    q += __shfl_xor(q, o, 64);
    m += __shfl_xor(m, o, 64);
  }
  __shared__ float sq[2], sm[2];
  if ((i & 63) == 0) { sq[i >> 6] = q; sm[i >> 6] = m; }
  __syncthreads();
  if (i == 0) {
    const float inv_m = 1.f / 131072.f;
    float mean = (sm[0] + sm[1]) * inv_m;
    float e2 = (sq[0] + sq[1]) * inv_m;
    float var = e2 - mean * mean;
    float rstd = rsqrtf(var + 1e-5f);
    float gs = gamma[c] * rstd;
    wsf[WS_GSCALE + c] = gs;
    wsf[WS_GBIAS + c] = beta[c] - mean * gs;
  }
}

// recompute x rows only at sampled indices, normalize + relu, gather coords
__global__ __launch_bounds__(256) void gather_k(
    const float* __restrict__ coord, const float* __restrict__ feat,
    const float* __restrict__ W, const float* __restrict__ wsf,
    const int* __restrict__ wsi, float* __restrict__ out)
{
  const int p = blockIdx.x, t = threadIdx.x;
  const int b = p >> 11;
  const int idx = wsi[p];
  const size_t row = (size_t)b * NPT + idx;
  __shared__ float lf[CIN];
  if (t < CIN) lf[t] = feat[row * CIN + t];
  __syncthreads();
  const float* Wc = W + t * CIN;
  float acc = 0.f;
#pragma unroll 8
  for (int k = 0; k < CIN; k += 4) {
    float4 w4 = *(const float4*)(Wc + k);
    acc += lf[k] * w4.x + lf[k + 1] * w4.y + lf[k + 2] * w4.z + lf[k + 3] * w4.w;
  }
  float y = fmaxf(fmaf(acc, wsf[WS_GSCALE + t], wsf[WS_GBIAS + t]), 0.f);
  out[OUT_FEAT + (size_t)p * COUT + t] = y;
  if (t < 3) out[OUT_COORD + p * 3 + t] = coord[row * 3 + t];
  if (p == 0 && t < 4) out[OUT_OFFS + t] = (float)((t + 1) * NS);
}

extern "C" void kernel_launch(void* const* d_in, const int* in_sizes, int n_in,
                              void* d_out, int out_size, void* d_ws, size_t ws_size,
                              hipStream_t stream)
{
  const float* coord = (const float*)d_in[0];
  const float* feat  = (const float*)d_in[1];
  // d_in[2] = offset (implied by constants)
  const float* W     = (const float*)d_in[3];
  const float* gamma = (const float*)d_in[4];
  const float* beta  = (const float*)d_in[5];
  float* wsf = (float*)d_ws;
  int* wsi = (int*)(wsf + WS_IDX);
  float* out = (float*)d_out;

  // zero the Gram + column-sum accumulators (atomics accumulate into these)
  hipMemsetAsync(d_ws, 0, (WS_FSUM + 128) * sizeof(float), stream);

  fused1<<<NB + 128 + 8, THR, 0, stream>>>(coord, feat, wsf, wsi);
  finalize_k<<<COUT, 128, 0, stream>>>(W, gamma, beta, wsf);
  gather_k<<<NB * NS, 256, 0, stream>>>(coord, feat, W, wsf, wsi, out);
}

// Round 6
// 5331.177 us; speedup vs baseline: 1.6328x; 1.5055x over previous
//
#include <hip/hip_runtime.h>

#define NB 4
#define NPT 32768
#define HPT 16384         // points per half-cloud
#define CIN 128
#define COUT 256
#define NS 2048
#define THR 512
#define PPT 32            // points per thread (HPT / THR)
#define NG 8              // float4 distance groups per thread (PPT/4)

// ws float-offset layout
#define WS_G 0            // 128*128 Gram
#define WS_FSUM 16384     // 128 column sums
#define WS_SLOT 16512     // 16 x uint64 sync slots (= 32 floats)
#define WS_GSCALE 16544   // 256
#define WS_GBIAS 16800    // 256
#define WS_IDX 17056      // 8192 ints

// d_out float-offset layout
#define OUT_COORD 0
#define OUT_FEAT 24576
#define OUT_OFFS 2121728

// Rounds 1-5 established: the toolchain pins fused1 at 128 VGPRs no matter
// what (launch_bounds / amdgpu attrs / LDS size all ignored) -> any design
// needing more spills ~65 MB/launch through scratch. So design UNDER 128:
// 2 blocks per cloud, 32 pts/thread -> 96 coord VGPRs + ~30 temps fits.
// All 32 distances live in LDS as 8 float4 rows (b128 r/w). Cross-block
// argmax via agent-scope packed 64-bit keys (tag|dbits|32767-idx), parity
// double-buffered -- writer of iter k+2 provably happens-after partner
// consumed iter k, so slots can't be overwritten early. Round-4's crash
// was NOT this protocol: it was idx_out[0] left unwritten for clouds 1-3
// (poisoned index -> gather_k page fault). Fixed below.
__global__ __launch_bounds__(THR) void fused1(
    const float* __restrict__ coord, const float* __restrict__ feat,
    float* __restrict__ wsf, int* __restrict__ wsi,
    unsigned long long* __restrict__ slots)
{
  __shared__ float4 ldsd[NG][THR];   // 65536 B distance store
  __shared__ int s_widx[2];
  __shared__ int s_gmaxb[2];
  __shared__ int s_bcast;
  __shared__ float s_fs[4][128];

  const int bid = blockIdx.x;
  const int t = threadIdx.x;
  const bool is_fps = (bid < 4) || (bid >= 8 && bid < 12);

  if (is_fps) {
    // ---------------- FPS: cloud cl, half h ----------------
    const int cl = bid & 3;
    const int h = bid >> 3;                    // pair (b, b+8): same XCD under %8
    const int gbase = h * HPT;
    const float* xyz = coord + (size_t)cl * NPT * 3;
    int* idx_out = wsi + cl * NS;
    unsigned long long* slot = slots + cl * 4; // [h][parity]

    float px[PPT], py[PPT], pz[PPT];
#pragma unroll
    for (int j = 0; j < PPT; ++j) {
      int p = gbase + j * THR + t;
      px[j] = xyz[p * 3 + 0];
      py[j] = xyz[p * 3 + 1];
      pz[j] = xyz[p * 3 + 2];
    }
#pragma unroll
    for (int g = 0; g < NG; ++g)
      ldsd[g][t] = make_float4(1e10f, 1e10f, 1e10f, 1e10f);
    if (t == 0) {
      if (h == 0) idx_out[0] = 0;              // EVERY cloud (round-4 bugfix)
      s_widx[0] = s_widx[1] = 0x7fffffff;
      s_gmaxb[0] = s_gmaxb[1] = 0;             // d >= 0 -> float bits monotone
    }
    float cx = xyz[0], cy = xyz[1], cz = xyz[2];  // same-address broadcast
    __syncthreads();

    const int lane = t & 63;
    for (int it = 1; it < NS; ++it) {
      const int par = it & 1;
      float mxa = -1.f, mxb = -1.f;
      // exact numpy-f32 distance: plain muls (asm blocks fma contraction),
      // (sx+sy)+sz, v_min_f32 update. Distances batched 4/thread in LDS.
#pragma unroll
      for (int g = 0; g < NG; ++g) {
        float4 d = ldsd[g][t];                 // ds_read_b128
        float nd[4];
#pragma unroll
        for (int k = 0; k < 4; ++k) {
          const int j = 4 * g + k;
          float dx = px[j] - cx, dy = py[j] - cy, dz = pz[j] - cz;
          float sx = dx * dx, sy = dy * dy, sz = dz * dz;
          asm volatile("" : "+v"(sx), "+v"(sy), "+v"(sz));
          float dist = (sx + sy) + sz;
          nd[k] = fminf(k == 0 ? d.x : k == 1 ? d.y : k == 2 ? d.z : d.w, dist);
        }
        ldsd[g][t] = make_float4(nd[0], nd[1], nd[2], nd[3]);  // ds_write_b128
        mxa = fmaxf(mxa, fmaxf(nd[0], nd[1]));
        mxb = fmaxf(mxb, fmaxf(nd[2], nd[3]));
      }
      float lmax = fmaxf(mxa, mxb);
      // exact block max (fmax tree has no rounding)
      float wm = lmax;
#pragma unroll
      for (int o = 32; o > 0; o >>= 1) wm = fmaxf(wm, __shfl_xor(wm, o, 64));
      if (lane == 0) atomicMax(&s_gmaxb[par], __float_as_int(wm));
      __syncthreads();                                   // B0
      if (t == 0) { s_gmaxb[par ^ 1] = 0; s_widx[par ^ 1] = 0x7fffffff; }
      const float gmax = __int_as_float(s_gmaxb[par]);
      if (lmax == gmax) {                                // candidate waves only
        int best = 0x7fffffff;
#pragma unroll
        for (int g = 0; g < NG; ++g) {
          float4 d = ldsd[g][t];
          if (d.x == gmax) best = min(best, gbase + (4 * g + 0) * THR + t);
          if (d.y == gmax) best = min(best, gbase + (4 * g + 1) * THR + t);
          if (d.z == gmax) best = min(best, gbase + (4 * g + 2) * THR + t);
          if (d.w == gmax) best = min(best, gbase + (4 * g + 3) * THR + t);
        }
        atomicMin(&s_widx[par], best);   // global idx; min == np first-occurrence
      }
      __syncthreads();                                   // B1
      if (t == 0) {
        // self-contained key: it<<48 | dbits<<15 | (32767 - idx)
        unsigned long long mine =
            ((unsigned long long)it << 48) |
            ((unsigned long long)(unsigned)s_gmaxb[par] << 15) |
            (unsigned)(32767 - s_widx[par]);
        __hip_atomic_store(&slot[h * 2 + par], mine,
                           __ATOMIC_RELAXED, __HIP_MEMORY_SCOPE_AGENT);
        unsigned long long other;
        do {
          other = __hip_atomic_load(&slot[(1 - h) * 2 + par],
                                    __ATOMIC_RELAXED, __HIP_MEMORY_SCOPE_AGENT);
        } while ((other >> 48) != (unsigned long long)it);
        unsigned long long win = mine > other ? mine : other;
        int widx = 32767 - (int)(win & 0x7fff);
        s_bcast = widx;
        if (h == 0) idx_out[it] = widx;
      }
      __syncthreads();                                   // B2
      const int widx = s_bcast;
      cx = xyz[widx * 3 + 0];                 // same-address broadcast load
      cy = xyz[widx * 3 + 1];
      cz = xyz[widx * 3 + 2];
    }
  } else {
    const int g = (bid < 8) ? (bid - 4) : (bid - 8);     // 0..135
    if (g < 128) {
      // ---------------- Gram partial: G += chunk^T chunk ----------------
      const float* fr = feat + (size_t)g * 1024 * CIN;
      const int ti = (t & 31) * 4;
      const int tj = (t >> 5) * 8;
      float acc[4][8];
#pragma unroll
      for (int a = 0; a < 4; ++a)
#pragma unroll
        for (int b2 = 0; b2 < 8; ++b2) acc[a][b2] = 0.f;
#pragma unroll 4
      for (int r = 0; r < 1024; ++r) {
        const float* rowp = fr + r * CIN;
        float4 a4 = *(const float4*)(rowp + ti);
        float4 b4 = *(const float4*)(rowp + tj);
        float4 b5 = *(const float4*)(rowp + tj + 4);
        float av[4] = {a4.x, a4.y, a4.z, a4.w};
        float bv[8] = {b4.x, b4.y, b4.z, b4.w, b5.x, b5.y, b5.z, b5.w};
#pragma unroll
        for (int a = 0; a < 4; ++a)
#pragma unroll
          for (int b2 = 0; b2 < 8; ++b2) acc[a][b2] += av[a] * bv[b2];
      }
      float* G = wsf + WS_G;
#pragma unroll
      for (int a = 0; a < 4; ++a)
#pragma unroll
        for (int b2 = 0; b2 < 8; ++b2)
          atomicAdd(&G[(ti + a) * CIN + (tj + b2)], acc[a][b2]);
    } else {
      // ---------------- column sums of feat ----------------
      const int fb = g - 128;             // 0..7
      const size_t base = (size_t)fb * 16384;
      const int c = t & 127, rg = t >> 7;
      float s = 0.f;
      for (int r = rg; r < 16384; r += 4)
        s += feat[(base + r) * CIN + c];
      s_fs[rg][c] = s;
      __syncthreads();
      if (t < 128) {
        float v = s_fs[0][t] + s_fs[1][t] + s_fs[2][t] + s_fs[3][t];
        atomicAdd(&wsf[WS_FSUM + t], v);
      }
    }
  }
}

// mean[c] = (fsum . W[c]) / M ; E[x^2][c] = W[c]^T G W[c] / M
__global__ __launch_bounds__(128) void finalize_k(
    const float* __restrict__ W, const float* __restrict__ gamma,
    const float* __restrict__ beta, float* __restrict__ wsf)
{
  const int c = blockIdx.x, i = threadIdx.x;
  const float* G = wsf + WS_G;
  const float* fsum = wsf + WS_FSUM;
  const float* Gi = G + i * CIN;
  const float* Wc = W + c * CIN;
  float td = 0.f;
#pragma unroll 8
  for (int j = 0; j < CIN; j += 4) {
    float4 g4 = *(const float4*)(Gi + j);
    float4 w4 = *(const float4*)(Wc + j);
    td += g4.x * w4.x + g4.y * w4.y + g4.z * w4.z + g4.w * w4.w;
  }
  const float wci = Wc[i];
  float q = wci * td;
  float m = fsum[i] * wci;
#pragma unroll
  for (int o = 32; o > 0; o >>= 1) {
    q += __shfl_xor(q, o, 64);
    m += __shfl_xor(m, o, 64);
  }
  __shared__ float sq[2], sm[2];
  if ((i & 63) == 0) { sq[i >> 6] = q; sm[i >> 6] = m; }
  __syncthreads();
  if (i == 0) {
    const float inv_m = 1.f / 131072.f;
    float mean = (sm[0] + sm[1]) * inv_m;
    float e2 = (sq[0] + sq[1]) * inv_m;
    float var = e2 - mean * mean;
    float rstd = rsqrtf(var + 1e-5f);
    float gs = gamma[c] * rstd;
    wsf[WS_GSCALE + c] = gs;
    wsf[WS_GBIAS + c] = beta[c] - mean * gs;
  }
}

// recompute x rows only at sampled indices, normalize + relu, gather coords
__global__ __launch_bounds__(256) void gather_k(
    const float* __restrict__ coord, const float* __restrict__ feat,
    const float* __restrict__ W, const float* __restrict__ wsf,
    const int* __restrict__ wsi, float* __restrict__ out)
{
  const int p = blockIdx.x, t = threadIdx.x;
  const int b = p >> 11;
  const int idx = wsi[p];
  const size_t row = (size_t)b * NPT + idx;
  __shared__ float lf[CIN];
  if (t < CIN) lf[t] = feat[row * CIN + t];
  __syncthreads();
  const float* Wc = W + t * CIN;
  float acc = 0.f;
#pragma unroll 8
  for (int k = 0; k < CIN; k += 4) {
    float4 w4 = *(const float4*)(Wc + k);
    acc += lf[k] * w4.x + lf[k + 1] * w4.y + lf[k + 2] * w4.z + lf[k + 3] * w4.w;
  }
  float y = fmaxf(fmaf(acc, wsf[WS_GSCALE + t], wsf[WS_GBIAS + t]), 0.f);
  out[OUT_FEAT + (size_t)p * COUT + t] = y;
  if (t < 3) out[OUT_COORD + p * 3 + t] = coord[row * 3 + t];
  if (p == 0 && t < 4) out[OUT_OFFS + t] = (float)((t + 1) * NS);
}

extern "C" void kernel_launch(void* const* d_in, const int* in_sizes, int n_in,
                              void* d_out, int out_size, void* d_ws, size_t ws_size,
                              hipStream_t stream)
{
  const float* coord = (const float*)d_in[0];
  const float* feat  = (const float*)d_in[1];
  // d_in[2] = offset (implied by constants)
  const float* W     = (const float*)d_in[3];
  const float* gamma = (const float*)d_in[4];
  const float* beta  = (const float*)d_in[5];
  float* wsf = (float*)d_ws;
  int* wsi = (int*)(wsf + WS_IDX);
  unsigned long long* slots = (unsigned long long*)(wsf + WS_SLOT);
  float* out = (float*)d_out;

  // zero Gram + colsum accumulators AND sync slots (kills stale tags
  // across graph replays; stream-ordered before fused1)
  hipMemsetAsync(d_ws, 0, (WS_SLOT + 32) * sizeof(float), stream);

  fused1<<<144, THR, 0, stream>>>(coord, feat, wsf, wsi, slots);
  finalize_k<<<COUT, 128, 0, stream>>>(W, gamma, beta, wsf);
  gather_k<<<NB * NS, 256, 0, stream>>>(coord, feat, W, wsf, wsi, out);
}

// Round 7
// 5139.683 us; speedup vs baseline: 1.6936x; 1.0373x over previous
//
#include <hip/hip_runtime.h>

#define NB 4
#define NPT 32768
#define QPT 8192          // points per quarter-cloud
#define CIN 128
#define COUT 256
#define NS 2048
#define THR 512
#define PPT 16            // points per thread (QPT / THR)

// ws float-offset layout
#define WS_G 0            // 128*128 Gram
#define WS_FSUM 16384     // 128 column sums
#define WS_SLOT 16512     // 32 x uint64 sync slots (= 64 floats)
#define WS_GSCALE 16576   // 256
#define WS_GBIAS 16832    // 256
#define WS_IDX 17088      // 8192 ints

// d_out float-offset layout
#define OUT_COORD 0
#define OUT_FEAT 24576
#define OUT_OFFS 2121728

// Design facts established rounds 1-6:
//  * toolchain pins this kernel's VGPR budget at 128; design under it.
//  * WRITE_SIZE ~66 MB is the Gram stage's 2.1M memory-side atomics
//    (cross-XCD coherent), NOT spills; it is expected and harmless.
//  * 4 blocks/cloud x 16 pts/thread -> coords(48)+dists(16)+temps fit in
//    regs entirely: no LDS distance store, no post-reduce rescan (argmax
//    tracked during the min-update), 2 barriers/iter.
//  * cross-block argmax: packed u64 key  it<<48 | dbits<<15 | (32767-gidx)
//    (monotone: bigger dist wins, tie -> lower index = np first occurrence),
//    per-(block,parity) slots, agent scope; writer of iter k+2 provably
//    happens-after all partners consumed iter k (pairwise, as in round 6).
__global__ __launch_bounds__(THR) void fused1(
    const float* __restrict__ coord, const float* __restrict__ feat,
    float* __restrict__ wsf, int* __restrict__ wsi,
    unsigned long long* __restrict__ slots)
{
  __shared__ unsigned long long s_key[2];
  __shared__ int s_bcast;
  __shared__ float s_fs[4][128];

  const int bid = blockIdx.x;
  const int t = threadIdx.x;
  const bool is_fps = (bid < 32) && ((bid & 7) < 4);

  if (is_fps) {
    // ---------------- FPS: cloud cl, quarter h ----------------
    const int cl = bid & 3;
    const int h = bid >> 3;                    // 0..3; {cl, cl+8, cl+16, cl+24}
    const int gbase = h * QPT;
    const float* xyz = coord + (size_t)cl * NPT * 3;
    int* idx_out = wsi + cl * NS;
    unsigned long long* slot = slots + cl * 8; // [h][parity]

    float px[PPT], py[PPT], pz[PPT], dv[PPT];
#pragma unroll
    for (int j = 0; j < PPT; ++j) {
      int p = gbase + j * THR + t;
      px[j] = xyz[p * 3 + 0];
      py[j] = xyz[p * 3 + 1];
      pz[j] = xyz[p * 3 + 2];
      dv[j] = 1e10f;
    }
    if (t == 0) {
      if (h == 0) idx_out[0] = 0;              // every cloud writes sample 0
      s_key[0] = s_key[1] = 0ull;
    }
    float cx = xyz[0], cy = xyz[1], cz = xyz[2];   // same-address broadcast
    __syncthreads();

    const int lane = t & 63;
    for (int it = 1; it < NS; ++it) {
      const int par = it & 1;
      float bd = -1.f;
      int bj = 0;
      // exact numpy-f32 distance: plain muls (asm blocks fma contraction),
      // (sx+sy)+sz, v_min_f32 update; argmax tracked inline (strict > keeps
      // the lowest j = lowest global index within this thread's stride).
#pragma unroll
      for (int j = 0; j < PPT; ++j) {
        float dx = px[j] - cx, dy = py[j] - cy, dz = pz[j] - cz;
        float sx = dx * dx, sy = dy * dy, sz = dz * dz;
        asm volatile("" : "+v"(sx), "+v"(sy), "+v"(sz));
        float nd = fminf(dv[j], (sx + sy) + sz);
        dv[j] = nd;
        if (nd > bd) { bd = nd; bj = j; }
      }
      const int gidx = gbase + bj * THR + t;
      unsigned long long key =
          ((unsigned long long)(unsigned)__float_as_int(bd) << 15) |
          (unsigned)(32767 - gidx);
      // exact wave argmax (u64 compare: dist bits dominate, then inv idx)
#pragma unroll
      for (int o = 32; o > 0; o >>= 1) {
        unsigned long long ok = __shfl_xor(key, o, 64);
        key = ok > key ? ok : key;
      }
      if (lane == 0) atomicMax(&s_key[par], key);
      __syncthreads();                                   // B0
      if (t == 0) {
        s_key[par ^ 1] = 0ull;                           // reset other parity
        unsigned long long mine =
            ((unsigned long long)it << 48) | s_key[par];
        __hip_atomic_store(&slot[h * 2 + par], mine,
                           __ATOMIC_RELAXED, __HIP_MEMORY_SCOPE_AGENT);
        unsigned long long best = mine;
        unsigned got = 1u << h;
        while (got != 0xFu) {
#pragma unroll
          for (int p = 0; p < 4; ++p) {
            if (!(got & (1u << p))) {
              unsigned long long v =
                  __hip_atomic_load(&slot[p * 2 + par],
                                    __ATOMIC_RELAXED, __HIP_MEMORY_SCOPE_AGENT);
              if ((v >> 48) == (unsigned long long)it) {
                got |= 1u << p;
                if (v > best) best = v;
              }
            }
          }
        }
        int widx = 32767 - (int)(best & 0x7fff);
        s_bcast = widx;
        if (h == 0) idx_out[it] = widx;
      }
      __syncthreads();                                   // B1
      const int widx = s_bcast;
      cx = xyz[widx * 3 + 0];                 // same-address broadcast load
      cy = xyz[widx * 3 + 1];
      cz = xyz[widx * 3 + 2];
    }
  } else {
    // non-FPS linear index: 16 fillers inside bid<32, rest from 32 up
    const int g = (bid < 32) ? ((bid >> 3) * 4 + (bid & 7) - 4) : (bid - 16);
    if (g < 128) {
      // ---------------- Gram partial: G += chunk^T chunk ----------------
      const float* fr = feat + (size_t)g * 1024 * CIN;
      const int ti = (t & 31) * 4;
      const int tj = (t >> 5) * 8;
      float acc[4][8];
#pragma unroll
      for (int a = 0; a < 4; ++a)
#pragma unroll
        for (int b2 = 0; b2 < 8; ++b2) acc[a][b2] = 0.f;
#pragma unroll 4
      for (int r = 0; r < 1024; ++r) {
        const float* rowp = fr + r * CIN;
        float4 a4 = *(const float4*)(rowp + ti);
        float4 b4 = *(const float4*)(rowp + tj);
        float4 b5 = *(const float4*)(rowp + tj + 4);
        float av[4] = {a4.x, a4.y, a4.z, a4.w};
        float bv[8] = {b4.x, b4.y, b4.z, b4.w, b5.x, b5.y, b5.z, b5.w};
#pragma unroll
        for (int a = 0; a < 4; ++a)
#pragma unroll
          for (int b2 = 0; b2 < 8; ++b2) acc[a][b2] += av[a] * bv[b2];
      }
      float* G = wsf + WS_G;
#pragma unroll
      for (int a = 0; a < 4; ++a)
#pragma unroll
        for (int b2 = 0; b2 < 8; ++b2)
          atomicAdd(&G[(ti + a) * CIN + (tj + b2)], acc[a][b2]);
    } else {
      // ---------------- column sums of feat ----------------
      const int fb = g - 128;             // 0..7
      const size_t base = (size_t)fb * 16384;
      const int c = t & 127, rg = t >> 7;
      float s = 0.f;
      for (int r = rg; r < 16384; r += 4)
        s += feat[(base + r) * CIN + c];
      s_fs[rg][c] = s;
      __syncthreads();
      if (t < 128) {
        float v = s_fs[0][t] + s_fs[1][t] + s_fs[2][t] + s_fs[3][t];
        atomicAdd(&wsf[WS_FSUM + t], v);
      }
    }
  }
}

// mean[c] = (fsum . W[c]) / M ; E[x^2][c] = W[c]^T G W[c] / M
__global__ __launch_bounds__(128) void finalize_k(
    const float* __restrict__ W, const float* __restrict__ gamma,
    const float* __restrict__ beta, float* __restrict__ wsf)
{
  const int c = blockIdx.x, i = threadIdx.x;
  const float* G = wsf + WS_G;
  const float* fsum = wsf + WS_FSUM;
  const float* Gi = G + i * CIN;
  const float* Wc = W + c * CIN;
  float td = 0.f;
#pragma unroll 8
  for (int j = 0; j < CIN; j += 4) {
    float4 g4 = *(const float4*)(Gi + j);
    float4 w4 = *(const float4*)(Wc + j);
    td += g4.x * w4.x + g4.y * w4.y + g4.z * w4.z + g4.w * w4.w;
  }
  const float wci = Wc[i];
  float q = wci * td;
  float m = fsum[i] * wci;
#pragma unroll
  for (int o = 32; o > 0; o >>= 1) {
    q += __shfl_xor(q, o, 64);
    m += __shfl_xor(m, o, 64);
  }
  __shared__ float sq[2], sm[2];
  if ((i & 63) == 0) { sq[i >> 6] = q; sm[i >> 6] = m; }
  __syncthreads();
  if (i == 0) {
    const float inv_m = 1.f / 131072.f;
    float mean = (sm[0] + sm[1]) * inv_m;
    float e2 = (sq[0] + sq[1]) * inv_m;
    float var = e2 - mean * mean;
    float rstd = rsqrtf(var + 1e-5f);
    float gs = gamma[c] * rstd;
    wsf[WS_GSCALE + c] = gs;
    wsf[WS_GBIAS + c] = beta[c] - mean * gs;
  }
}

// recompute x rows only at sampled indices, normalize + relu, gather coords
__global__ __launch_bounds__(256) void gather_k(
    const float* __restrict__ coord, const float* __restrict__ feat,
    const float* __restrict__ W, const float* __restrict__ wsf,
    const int* __restrict__ wsi, float* __restrict__ out)
{
  const int p = blockIdx.x, t = threadIdx.x;
  const int b = p >> 11;
  const int idx = wsi[p];
  const size_t row = (size_t)b * NPT + idx;
  __shared__ float lf[CIN];
  if (t < CIN) lf[t] = feat[row * CIN + t];
  __syncthreads();
  const float* Wc = W + t * CIN;
  float acc = 0.f;
#pragma unroll 8
  for (int k = 0; k < CIN; k += 4) {
    float4 w4 = *(const float4*)(Wc + k);
    acc += lf[k] * w4.x + lf[k + 1] * w4.y + lf[k + 2] * w4.z + lf[k + 3] * w4.w;
  }
  float y = fmaxf(fmaf(acc, wsf[WS_GSCALE + t], wsf[WS_GBIAS + t]), 0.f);
  out[OUT_FEAT + (size_t)p * COUT + t] = y;
  if (t < 3) out[OUT_COORD + p * 3 + t] = coord[row * 3 + t];
  if (p == 0 && t < 4) out[OUT_OFFS + t] = (float)((t + 1) * NS);
}

extern "C" void kernel_launch(void* const* d_in, const int* in_sizes, int n_in,
                              void* d_out, int out_size, void* d_ws, size_t ws_size,
                              hipStream_t stream)
{
  const float* coord = (const float*)d_in[0];
  const float* feat  = (const float*)d_in[1];
  // d_in[2] = offset (implied by constants)
  const float* W     = (const float*)d_in[3];
  const float* gamma = (const float*)d_in[4];
  const float* beta  = (const float*)d_in[5];
  float* wsf = (float*)d_ws;
  int* wsi = (int*)(wsf + WS_IDX);
  unsigned long long* slots = (unsigned long long*)(wsf + WS_SLOT);
  float* out = (float*)d_out;

  // zero Gram + colsum accumulators AND sync slots (kills stale tags
  // across graph replays; stream-ordered before fused1)
  hipMemsetAsync(d_ws, 0, (WS_SLOT + 64) * sizeof(float), stream);

  fused1<<<152, THR, 0, stream>>>(coord, feat, wsf, wsi, slots);
  finalize_k<<<COUT, 128, 0, stream>>>(W, gamma, beta, wsf);
  gather_k<<<NB * NS, 256, 0, stream>>>(coord, feat, W, wsf, wsi, out);
}

// Round 8
// 4746.011 us; speedup vs baseline: 1.8341x; 1.0829x over previous
//
#include <hip/hip_runtime.h>

#define NB 4
#define NPT 32768
#define QPT 8192          // points per quarter-cloud
#define CIN 128
#define COUT 256
#define NS 2048
#define THR 512
#define PPT 16            // points per thread (QPT / THR)

// ws float-offset layout
#define WS_G 0            // 128*128 Gram
#define WS_FSUM 16384     // 128 column sums
#define WS_SLOT 16512     // 32 x uint64 sync slots (= 64 floats)
#define WS_GSCALE 16576   // 256
#define WS_GBIAS 16832    // 256
#define WS_IDX 17088      // 8192 ints

// d_out float-offset layout
#define OUT_COORD 0
#define OUT_FEAT 24576
#define OUT_OFFS 2121728

// Established rounds 1-7:
//  * VGPR budget pinned by toolchain; 4 blocks/cloud x 16 pts/thread fits.
//  * WRITE_SIZE ~66 MB = Gram's 2.1M memory-side atomics. Expected.
//  * agent-scope atomic loads are serviced memory-side (~600-900 cyc RT):
//    round-7 FETCH delta matches poll traffic exactly.
//  * round-7 sync floor ~1.8 us/iter = t0-serialized exchange + 2 barriers.
// This round: ONE barrier per iter. Keys carry the iteration tag
// (it<<48 | dbits<<15 | (32767-gidx)), monotone -> stale values lose
// atomicMax automatically (no parity resets). After B0 the unique winner
// thread stores the block key straight to its global slot; ALL threads
// poll the 4 same-parity slots (wave-uniform -> coalesced broadcast) and
// merge locally -- no t0 funnel, no B1, no LDS bcast. Slot reuse at
// parity distance 2 is safe: passing poll(it+1) requires every block's
// store(it+1) which happens-after its B0(it+1) which happens-after all
// its waves exited poll(it).
__global__ __launch_bounds__(THR) void fused1(
    const float* __restrict__ coord, const float* __restrict__ feat,
    float* __restrict__ wsf, int* __restrict__ wsi,
    unsigned long long* __restrict__ slots)
{
  __shared__ unsigned long long s_key[2];
  __shared__ float s_fs[4][128];

  const int bid = blockIdx.x;
  const int t = threadIdx.x;
  const bool is_fps = (bid < 32) && ((bid & 7) < 4);

  if (is_fps) {
    // ---------------- FPS: cloud cl, quarter h ----------------
    const int cl = bid & 3;
    const int h = bid >> 3;                    // 0..3
    const int gbase = h * QPT;
    const float* xyz = coord + (size_t)cl * NPT * 3;
    int* idx_out = wsi + cl * NS;
    unsigned long long* slot = slots + cl * 8; // [par][h], par-major 32B line

    float px[PPT], py[PPT], pz[PPT], dv[PPT];
#pragma unroll
    for (int j = 0; j < PPT; ++j) {
      int p = gbase + j * THR + t;
      px[j] = xyz[p * 3 + 0];
      py[j] = xyz[p * 3 + 1];
      pz[j] = xyz[p * 3 + 2];
      dv[j] = 1e10f;
    }
    if (t == 0) {
      if (h == 0) idx_out[0] = 0;              // every cloud writes sample 0
      s_key[0] = s_key[1] = 0ull;              // tag 0 < any it>=1
    }
    float cx = xyz[0], cy = xyz[1], cz = xyz[2];   // same-address broadcast
    __syncthreads();

    const int lane = t & 63;
    for (int it = 1; it < NS; ++it) {
      const int par = it & 1;
      const unsigned long long utag = (unsigned long long)it;
      float bd = -1.f;
      int bj = 0;
      // exact numpy-f32 distance: plain muls (asm blocks fma contraction),
      // (sx+sy)+sz, v_min_f32 update; argmax tracked inline (strict > keeps
      // lowest j = lowest global index within this thread's stride).
#pragma unroll
      for (int j = 0; j < PPT; ++j) {
        float dx = px[j] - cx, dy = py[j] - cy, dz = pz[j] - cz;
        float sx = dx * dx, sy = dy * dy, sz = dz * dz;
        asm volatile("" : "+v"(sx), "+v"(sy), "+v"(sz));
        float nd = fminf(dv[j], (sx + sy) + sz);
        dv[j] = nd;
        if (nd > bd) { bd = nd; bj = j; }
      }
      const int gidx = gbase + bj * THR + t;
      // tagged monotone key: bigger dist wins, tie -> lower idx (np.argmax)
      const unsigned long long tkey =
          (utag << 48) |
          ((unsigned long long)(unsigned)__float_as_int(bd) << 15) |
          (unsigned)(32767 - gidx);
      unsigned long long wkey = tkey;
#pragma unroll
      for (int o = 32; o > 0; o >>= 1) {
        unsigned long long ok = __shfl_xor(wkey, o, 64);
        wkey = ok > wkey ? ok : wkey;
      }
      if (lane == 0) atomicMax(&s_key[par], wkey);
      __syncthreads();                         // the ONLY barrier per iter
      const unsigned long long skey = s_key[par];
      if (tkey == skey)                        // unique winner thread
        __hip_atomic_store(&slot[par * 4 + h], skey,
                           __ATOMIC_RELAXED, __HIP_MEMORY_SCOPE_AGENT);
      unsigned long long v0, v1, v2, v3;
      do {                                     // all threads poll, coalesced
        v0 = __hip_atomic_load(&slot[par * 4 + 0],
                               __ATOMIC_RELAXED, __HIP_MEMORY_SCOPE_AGENT);
        v1 = __hip_atomic_load(&slot[par * 4 + 1],
                               __ATOMIC_RELAXED, __HIP_MEMORY_SCOPE_AGENT);
        v2 = __hip_atomic_load(&slot[par * 4 + 2],
                               __ATOMIC_RELAXED, __HIP_MEMORY_SCOPE_AGENT);
        v3 = __hip_atomic_load(&slot[par * 4 + 3],
                               __ATOMIC_RELAXED, __HIP_MEMORY_SCOPE_AGENT);
      } while ((v0 >> 48) != utag || (v1 >> 48) != utag ||
               (v2 >> 48) != utag || (v3 >> 48) != utag);
      const unsigned long long b01 = v0 > v1 ? v0 : v1;
      const unsigned long long b23 = v2 > v3 ? v2 : v3;
      const unsigned long long best = b01 > b23 ? b01 : b23;
      const int widx = 32767 - (int)(best & 0x7fff);
      if (h == 0 && t == 0) idx_out[it] = widx;
      cx = xyz[widx * 3 + 0];                  // same-address broadcast load
      cy = xyz[widx * 3 + 1];
      cz = xyz[widx * 3 + 2];
    }
  } else {
    // non-FPS linear index: 16 fillers inside bid<32, rest from 32 up
    const int g = (bid < 32) ? ((bid >> 3) * 4 + (bid & 7) - 4) : (bid - 16);
    if (g < 128) {
      // ---------------- Gram partial: G += chunk^T chunk ----------------
      const float* fr = feat + (size_t)g * 1024 * CIN;
      const int ti = (t & 31) * 4;
      const int tj = (t >> 5) * 8;
      float acc[4][8];
#pragma unroll
      for (int a = 0; a < 4; ++a)
#pragma unroll
        for (int b2 = 0; b2 < 8; ++b2) acc[a][b2] = 0.f;
#pragma unroll 4
      for (int r = 0; r < 1024; ++r) {
        const float* rowp = fr + r * CIN;
        float4 a4 = *(const float4*)(rowp + ti);
        float4 b4 = *(const float4*)(rowp + tj);
        float4 b5 = *(const float4*)(rowp + tj + 4);
        float av[4] = {a4.x, a4.y, a4.z, a4.w};
        float bv[8] = {b4.x, b4.y, b4.z, b4.w, b5.x, b5.y, b5.z, b5.w};
#pragma unroll
        for (int a = 0; a < 4; ++a)
#pragma unroll
          for (int b2 = 0; b2 < 8; ++b2) acc[a][b2] += av[a] * bv[b2];
      }
      float* G = wsf + WS_G;
#pragma unroll
      for (int a = 0; a < 4; ++a)
#pragma unroll
        for (int b2 = 0; b2 < 8; ++b2)
          atomicAdd(&G[(ti + a) * CIN + (tj + b2)], acc[a][b2]);
    } else {
      // ---------------- column sums of feat ----------------
      const int fb = g - 128;             // 0..7
      const size_t base = (size_t)fb * 16384;
      const int c = t & 127, rg = t >> 7;
      float s = 0.f;
      for (int r = rg; r < 16384; r += 4)
        s += feat[(base + r) * CIN + c];
      s_fs[rg][c] = s;
      __syncthreads();
      if (t < 128) {
        float v = s_fs[0][t] + s_fs[1][t] + s_fs[2][t] + s_fs[3][t];
        atomicAdd(&wsf[WS_FSUM + t], v);
      }
    }
  }
}

// mean[c] = (fsum . W[c]) / M ; E[x^2][c] = W[c]^T G W[c] / M
__global__ __launch_bounds__(128) void finalize_k(
    const float* __restrict__ W, const float* __restrict__ gamma,
    const float* __restrict__ beta, float* __restrict__ wsf)
{
  const int c = blockIdx.x, i = threadIdx.x;
  const float* G = wsf + WS_G;
  const float* fsum = wsf + WS_FSUM;
  const float* Gi = G + i * CIN;
  const float* Wc = W + c * CIN;
  float td = 0.f;
#pragma unroll 8
  for (int j = 0; j < CIN; j += 4) {
    float4 g4 = *(const float4*)(Gi + j);
    float4 w4 = *(const float4*)(Wc + j);
    td += g4.x * w4.x + g4.y * w4.y + g4.z * w4.z + g4.w * w4.w;
  }
  const float wci = Wc[i];
  float q = wci * td;
  float m = fsum[i] * wci;
#pragma unroll
  for (int o = 32; o > 0; o >>= 1) {
    q += __shfl_xor(q, o, 64);
    m += __shfl_xor(m, o, 64);
  }
  __shared__ float sq[2], sm[2];
  if ((i & 63) == 0) { sq[i >> 6] = q; sm[i >> 6] = m; }
  __syncthreads();
  if (i == 0) {
    const float inv_m = 1.f / 131072.f;
    float mean = (sm[0] + sm[1]) * inv_m;
    float e2 = (sq[0] + sq[1]) * inv_m;
    float var = e2 - mean * mean;
    float rstd = rsqrtf(var + 1e-5f);
    float gs = gamma[c] * rstd;
    wsf[WS_GSCALE + c] = gs;
    wsf[WS_GBIAS + c] = beta[c] - mean * gs;
  }
}

// recompute x rows only at sampled indices, normalize + relu, gather coords
__global__ __launch_bounds__(256) void gather_k(
    const float* __restrict__ coord, const float* __restrict__ feat,
    const float* __restrict__ W, const float* __restrict__ wsf,
    const int* __restrict__ wsi, float* __restrict__ out)
{
  const int p = blockIdx.x, t = threadIdx.x;
  const int b = p >> 11;
  const int idx = wsi[p];
  const size_t row = (size_t)b * NPT + idx;
  __shared__ float lf[CIN];
  if (t < CIN) lf[t] = feat[row * CIN + t];
  __syncthreads();
  const float* Wc = W + t * CIN;
  float acc = 0.f;
#pragma unroll 8
  for (int k = 0; k < CIN; k += 4) {
    float4 w4 = *(const float4*)(Wc + k);
    acc += lf[k] * w4.x + lf[k + 1] * w4.y + lf[k + 2] * w4.z + lf[k + 3] * w4.w;
  }
  float y = fmaxf(fmaf(acc, wsf[WS_GSCALE + t], wsf[WS_GBIAS + t]), 0.f);
  out[OUT_FEAT + (size_t)p * COUT + t] = y;
  if (t < 3) out[OUT_COORD + p * 3 + t] = coord[row * 3 + t];
  if (p == 0 && t < 4) out[OUT_OFFS + t] = (float)((t + 1) * NS);
}

extern "C" void kernel_launch(void* const* d_in, const int* in_sizes, int n_in,
                              void* d_out, int out_size, void* d_ws, size_t ws_size,
                              hipStream_t stream)
{
  const float* coord = (const float*)d_in[0];
  const float* feat  = (const float*)d_in[1];
  // d_in[2] = offset (implied by constants)
  const float* W     = (const float*)d_in[3];
  const float* gamma = (const float*)d_in[4];
  const float* beta  = (const float*)d_in[5];
  float* wsf = (float*)d_ws;
  int* wsi = (int*)(wsf + WS_IDX);
  unsigned long long* slots = (unsigned long long*)(wsf + WS_SLOT);
  float* out = (float*)d_out;

  // zero Gram + colsum accumulators AND sync slots (kills stale tags
  // across graph replays; stream-ordered before fused1)
  hipMemsetAsync(d_ws, 0, (WS_SLOT + 64) * sizeof(float), stream);

  fused1<<<152, THR, 0, stream>>>(coord, feat, wsf, wsi, slots);
  finalize_k<<<COUT, 128, 0, stream>>>(W, gamma, beta, wsf);
  gather_k<<<NB * NS, 256, 0, stream>>>(coord, feat, W, wsf, wsi, out);
}